// Round 9
// baseline (251.588 us; speedup 1.0000x reference)
//
#include <hip/hip_runtime.h>

// Problem constants
#define S_   16384
#define T_   16384
#define B_   32
#define NEDGES (S_ * 64)       // 1,048,576
#define GP_  512               // producer blocks, 2048 edges each
#define EPG  2048              // edges per producer block
#define NBKT 512               // buckets of 32 targets
#define TPB  32                // targets per bucket

// weight = clip(att,0,1) * 0.9^delay, delay in [0,6). Exact bit-product.
__device__ __forceinline__ float edge_weight(float a, int d) {
  float w = fminf(fmaxf(a, 0.0f), 1.0f);
  float r = (d & 1) ? 0.9f : 1.0f;
  r = (d & 2) ? r * 0.81f   : r;
  r = (d & 4) ? r * 0.6561f : r;
  return w * r;
}

// ---------------------------------------------------------------------------
// K1: transpose 32 sources of spikes + LDS counting-sort of 2048 edges into
// 512 buckets + one contiguous 16 KB flush (unchanged from R8).
// rec[g][i]: {meta = tl<<14 | src, w_bits} grouped by bucket;
// ofse[g][bkt] = end<<16 | start.
__global__ __launch_bounds__(512) void produce(
    const float* __restrict__ spikes,
    const float* __restrict__ att,
    const int*   __restrict__ tgt,
    const int*   __restrict__ del,
    float*        __restrict__ spikesT,
    int2*         __restrict__ rec,
    unsigned int* __restrict__ ofse) {
  __shared__ float tile[32][33];
  __shared__ int4  sbuf4[EPG / 2];      // 16 KB: 2048 int2 records
  __shared__ int   cnt5[NBKT], cur5[NBKT], sofs5[NBKT];
  __shared__ int   wtot[8];
  int2* buf = (int2*)sbuf4;

  const int g   = blockIdx.x;
  const int tid = threadIdx.x;
  cnt5[tid] = 0;

  const int s0 = g * 32;
  {
    const int x = tid & 31, y = tid >> 5;
    tile[x][y]      = spikes[(size_t)y        * S_ + s0 + x];
    tile[x][y + 16] = spikes[(size_t)(y + 16) * S_ + s0 + x];
  }

  const int e4  = g * 512 + tid;
  int4   t = reinterpret_cast<const int4*>(tgt)[e4];
  float4 a = reinterpret_cast<const float4*>(att)[e4];
  int4   d = reinterpret_cast<const int4*>(del)[e4];
  const int src = e4 >> 4;

  __syncthreads();

  {
    const int b = tid & 31, j = tid >> 5;
    spikesT[(size_t)(s0 + j)      * 32 + b] = tile[j][b];
    spikesT[(size_t)(s0 + j + 16) * 32 + b] = tile[j + 16][b];
  }

  const int bk0 = t.x >> 5, bk1 = t.y >> 5, bk2 = t.z >> 5, bk3 = t.w >> 5;
  __hip_atomic_fetch_add(&cnt5[bk0], 1, __ATOMIC_RELAXED, __HIP_MEMORY_SCOPE_WORKGROUP);
  __hip_atomic_fetch_add(&cnt5[bk1], 1, __ATOMIC_RELAXED, __HIP_MEMORY_SCOPE_WORKGROUP);
  __hip_atomic_fetch_add(&cnt5[bk2], 1, __ATOMIC_RELAXED, __HIP_MEMORY_SCOPE_WORKGROUP);
  __hip_atomic_fetch_add(&cnt5[bk3], 1, __ATOMIC_RELAXED, __HIP_MEMORY_SCOPE_WORKGROUP);
  __syncthreads();

  int v = cnt5[tid];
  int incl = v;
#pragma unroll
  for (int off = 1; off < 64; off <<= 1) {
    int u = __shfl_up(incl, off);
    if ((tid & 63) >= off) incl += u;
  }
  if ((tid & 63) == 63) wtot[tid >> 6] = incl;
  __syncthreads();
  {
    int base = 0;
    const int wv = tid >> 6;
    for (int i = 0; i < wv; ++i) base += wtot[i];
    const int start = base + incl - v;
    sofs5[tid] = start;
    cur5[tid]  = start;
  }
  __syncthreads();

#define PUT(BK, TL, AV, DV)                                                   \
  {                                                                           \
    int p = __hip_atomic_fetch_add(&cur5[BK], 1, __ATOMIC_RELAXED,            \
                                   __HIP_MEMORY_SCOPE_WORKGROUP);             \
    buf[p] = make_int2(((TL) << 14) | src,                                    \
                       __float_as_int(edge_weight((AV), (DV))));              \
  }
  PUT(bk0, t.x & 31, a.x, d.x)
  PUT(bk1, t.y & 31, a.y, d.y)
  PUT(bk2, t.z & 31, a.z, d.z)
  PUT(bk3, t.w & 31, a.w, d.w)
#undef PUT
  __syncthreads();

  int4* recO = reinterpret_cast<int4*>(rec) + (size_t)g * (EPG / 2);
  recO[tid]       = sbuf4[tid];
  recO[tid + 512] = sbuf4[tid + 512];
  ofse[(size_t)g * NBKT + tid] =
      ((unsigned)cur5[tid] << 16) | (unsigned)sofs5[tid];
}

// ---------------------------------------------------------------------------
// K2: NO fine sort. Bucket k: half-wave hw streams its 32 slices; all 32
// lanes broadcast-read each 8 B record, compute w*spike, and do ONE
// half-wave-wide ds_add_f32 into acc[tl][b] (lane b -> bank b: conflict-free).
// Then padded-LDS transposed store to out. 512 blocks x 512 threads.
__global__ __launch_bounds__(512) void consume(
    const int2*  __restrict__ rec,
    const unsigned int* __restrict__ ofse,
    const float* __restrict__ spikesT,
    float* __restrict__ out) {
  __shared__ float acc[TPB][33];        // padded: transposed read conflict-free
  __shared__ unsigned sse[GP_];

  const int k   = blockIdx.x;
  const int tid = threadIdx.x;
  const int b   = tid & 31;
  const int hw  = tid >> 5;             // 0..15

  // zero accumulator (512 threads, 1056 floats)
  for (int i = tid; i < TPB * 33; i += 512) ((float*)acc)[i] = 0.0f;
  // slice directory: 512 parallel strided loads (one per thread, all in flight)
  sse[tid] = ofse[(size_t)tid * NBKT + k];
  __syncthreads();

  // stream records: half-wave hw handles slices hw, hw+16, hw+32, ...
  for (int it = 0; it < 32; ++it) {
    const int g = hw + it * 16;
    const unsigned u = sse[g];
    const int st = (int)(u & 0xFFFF);
    const int n  = (int)(u >> 16) - st;
    const int2* slice = rec + (size_t)g * EPG + st;
    for (int j = 0; j < n; ++j) {
      const int2 r = slice[j];          // 32-lane same-address broadcast
      const float v = __int_as_float(r.y) *
                      spikesT[(size_t)(r.x & 0x3FFF) * 32 + b];
      atomicAdd(&acc[(r.x >> 14) & 31][b], v);   // ds_add_f32, no return
    }
  }
  __syncthreads();

  // write out[b][k*32 + t] from acc[t][b]: lanes read stride-33 -> no conflict
  const int bb = tid >> 4;              // batch 0..31
  const int cc = (tid & 15) * 2;        // target pair
  float2 o2 = make_float2(acc[cc][bb], acc[cc + 1][bb]);
  *reinterpret_cast<float2*>(&out[(size_t)bb * T_ + k * 32 + cc]) = o2;
}

// ---------------------------------------------------------------------------
__global__ void zero_floats(float* __restrict__ p, int n) {
  int i = blockIdx.x * blockDim.x + threadIdx.x;
  if (i < n) p[i] = 0.0f;
}

// Emergency fallback (tiny ws): direct global atomics, weights inline.
__global__ void naive_kernel(const float* __restrict__ spikes,
                             const float* __restrict__ att,
                             const int*   __restrict__ tgt,
                             const int*   __restrict__ del,
                             float*       __restrict__ out) {
  int i = blockIdx.x * blockDim.x + threadIdx.x;
  if (i >= NEDGES) return;
  int   s = i >> 6;
  int   t = tgt[i];
  float w = edge_weight(att[i], del[i]);
  for (int b = 0; b < B_; ++b)
    unsafeAtomicAdd(&out[(size_t)b * T_ + t], w * spikes[(size_t)b * S_ + s]);
}

// ---------------------------------------------------------------------------
extern "C" void kernel_launch(void* const* d_in, const int* in_sizes, int n_in,
                              void* d_out, int out_size, void* d_ws, size_t ws_size,
                              hipStream_t stream) {
  const float* spikes = (const float*)d_in[0];
  const float* att    = (const float*)d_in[1];
  const int*   tgt    = (const int*)d_in[2];
  const int*   del    = (const int*)d_in[3];
  float*       out    = (float*)d_out;

  const size_t spikesT_bytes = (size_t)S_ * B_ * sizeof(float);         // 2 MB
  const size_t rec_bytes     = (size_t)NEDGES * sizeof(int2);           // 8 MB
  const size_t ofse_bytes    = (size_t)GP_ * NBKT * sizeof(unsigned);   // 1 MB
  const size_t need = spikesT_bytes + rec_bytes + ofse_bytes + 64;

  if (ws_size < need) {
    zero_floats<<<(B_ * T_ + 255) / 256, 256, 0, stream>>>(out, B_ * T_);
    naive_kernel<<<(NEDGES + 255) / 256, 256, 0, stream>>>(spikes, att, tgt, del, out);
    return;
  }

  char* p = (char*)d_ws;
  float*        spikesT = (float*)p;        p += spikesT_bytes;
  int2*         rec     = (int2*)p;         p += rec_bytes;
  unsigned int* ofse    = (unsigned int*)p;

  produce<<<GP_, 512, 0, stream>>>(spikes, att, tgt, del, spikesT, rec, ofse);
  consume<<<NBKT, 512, 0, stream>>>(rec, ofse, spikesT, out);
}

// Round 10
// 100.533 us; speedup vs baseline: 2.5026x; 2.5026x over previous
//
#include <hip/hip_runtime.h>

// Problem constants
#define S_   16384
#define T_   16384
#define B_   32
#define NEDGES (S_ * 64)       // 1,048,576
#define GP_  512               // producer blocks, 2048 edges each
#define EPG  2048              // edges per producer block
#define NBKT 512               // buckets of 32 targets
#define TPB  32                // targets per bucket
#define CAP_SRT 2432           // lambda=2048, +8.5 sigma

// weight = clip(att,0,1) * 0.9^delay, delay in [0,6). Exact bit-product.
__device__ __forceinline__ float edge_weight(float a, int d) {
  float w = fminf(fmaxf(a, 0.0f), 1.0f);
  float r = (d & 1) ? 0.9f : 1.0f;
  r = (d & 2) ? r * 0.81f   : r;
  r = (d & 4) ? r * 0.6561f : r;
  return w * r;
}

// ---------------------------------------------------------------------------
// K1: ONE LDS atomic per edge. Packed-u8 16384-bin histogram; the atomic's
// return value IS the record's rank within (block, target). Byte-scan gives
// exact positions -> LDS buffer emerges fully TARGET-sorted; contiguous flush.
// Outputs: rec[g][0..2048) {meta = rank<<19 | tl<<14 | src, w_bits},
//          cntg[g][4096] packed u8 per-target counts,
//          ofse[g][bkt] = end<<16 | start (bucket slice bounds).
__global__ __launch_bounds__(512) void produce(
    const float* __restrict__ spikes,
    const float* __restrict__ att,
    const int*   __restrict__ tgt,
    const int*   __restrict__ del,
    float*    __restrict__ spikesT,
    int2*     __restrict__ rec,
    unsigned* __restrict__ cntg,
    unsigned* __restrict__ ofse) {
  __shared__ float tile[32][33];             // 4.2 KB
  __shared__ int4  sbuf4[EPG / 2];           // 16 KB (2048 int2 records)
  __shared__ unsigned cntp[4096];            // 16 KB packed u8 x4 counts
  __shared__ unsigned short tofs[16384];     // 32 KB exclusive byte-prefix
  __shared__ int wtot[8];
  int2* buf = (int2*)sbuf4;

  const int g = blockIdx.x, tid = threadIdx.x;
#pragma unroll
  for (int i = 0; i < 8; ++i) cntp[tid + 512 * i] = 0u;

  // transpose sources [g*32, g*32+32)
  const int s0 = g * 32;
  {
    const int x = tid & 31, y = tid >> 5;
    tile[x][y]      = spikes[(size_t)y        * S_ + s0 + x];
    tile[x][y + 16] = spikes[(size_t)(y + 16) * S_ + s0 + x];
  }

  const int e4 = g * 512 + tid;
  int4   t = reinterpret_cast<const int4*>(tgt)[e4];
  float4 a = reinterpret_cast<const float4*>(att)[e4];
  int4   d = reinterpret_cast<const int4*>(del)[e4];
  const int src = e4 >> 4;                   // 4 consecutive edges: 1 source

  __syncthreads();                           // cntp + tile visible

  {
    const int b = tid & 31, j = tid >> 5;
    spikesT[(size_t)(s0 + j)      * 32 + b] = tile[j][b];
    spikesT[(size_t)(s0 + j + 16) * 32 + b] = tile[j + 16][b];
  }

  // hist + rank: ONE atomic lane-op per edge (returns old -> rank byte)
  int r0, r1, r2, r3;
  {
    unsigned o;
    o = __hip_atomic_fetch_add(&cntp[t.x >> 2], 1u << (8 * (t.x & 3)),
                               __ATOMIC_RELAXED, __HIP_MEMORY_SCOPE_WORKGROUP);
    r0 = (int)((o >> (8 * (t.x & 3))) & 0xFF);
    o = __hip_atomic_fetch_add(&cntp[t.y >> 2], 1u << (8 * (t.y & 3)),
                               __ATOMIC_RELAXED, __HIP_MEMORY_SCOPE_WORKGROUP);
    r1 = (int)((o >> (8 * (t.y & 3))) & 0xFF);
    o = __hip_atomic_fetch_add(&cntp[t.z >> 2], 1u << (8 * (t.z & 3)),
                               __ATOMIC_RELAXED, __HIP_MEMORY_SCOPE_WORKGROUP);
    r2 = (int)((o >> (8 * (t.z & 3))) & 0xFF);
    o = __hip_atomic_fetch_add(&cntp[t.w >> 2], 1u << (8 * (t.w & 3)),
                               __ATOMIC_RELAXED, __HIP_MEMORY_SCOPE_WORKGROUP);
    r3 = (int)((o >> (8 * (t.w & 3))) & 0xFF);
  }
  __syncthreads();

  // scan 16384 byte-counts; thread tid covers targets [32 tid, 32 tid+32)
  // (== bucket tid exactly)
  unsigned w[8];
  int tot = 0;
#pragma unroll
  for (int i = 0; i < 8; ++i) {
    w[i] = cntp[tid * 8 + i];
    tot += (w[i] & 0xFF) + ((w[i] >> 8) & 0xFF) + ((w[i] >> 16) & 0xFF) + (w[i] >> 24);
  }
  int incl = tot;
#pragma unroll
  for (int off = 1; off < 64; off <<= 1) {
    int u = __shfl_up(incl, off);
    if ((tid & 63) >= off) incl += u;
  }
  if ((tid & 63) == 63) wtot[tid >> 6] = incl;
  __syncthreads();
  int base = 0;
  for (int i = 0; i < (tid >> 6); ++i) base += wtot[i];
  const int start = base + incl - tot;
  int run = start;
#pragma unroll
  for (int i = 0; i < 8; ++i) {
#pragma unroll
    for (int bb = 0; bb < 4; ++bb) {
      tofs[tid * 32 + i * 4 + bb] = (unsigned short)run;
      run += (w[i] >> (8 * bb)) & 0xFF;
    }
  }
  ofse[(size_t)g * NBKT + tid] = ((unsigned)run << 16) | (unsigned)start;
#pragma unroll
  for (int i = 0; i < 8; ++i)
    cntg[(size_t)g * 4096 + tid + 512 * i] = cntp[tid + 512 * i];
  __syncthreads();                           // tofs ready

  // place records: position = tofs[t] + rank (unique, no atomics)
#define PUT(TT, RK, AV, DV)                                                   \
  {                                                                           \
    const int p = (int)tofs[TT] + (RK);                                       \
    buf[p] = make_int2((((RK) & 31) << 19) | (((TT) & 31) << 14) | src,       \
                       __float_as_int(edge_weight((AV), (DV))));              \
  }
  PUT(t.x, r0, a.x, d.x)
  PUT(t.y, r1, a.y, d.y)
  PUT(t.z, r2, a.z, d.z)
  PUT(t.w, r3, a.w, d.w)
#undef PUT
  __syncthreads();

  int4* recO = reinterpret_cast<int4*>(rec) + (size_t)g * (EPG / 2);
  recO[tid]       = sbuf4[tid];
  recO[tid + 512] = sbuf4[tid + 512];
}

// ---------------------------------------------------------------------------
// K2: ZERO atomics. Rebuild per-(target, producer) prefix lpos from cntg,
// compute each record's exact srt slot = ofs[tl] + lpos[tl][g] + rank,
// plain ds_write, then register gather + direct transposed out write.
__global__ __launch_bounds__(512) void consume(
    const int2*     __restrict__ rec,
    const unsigned* __restrict__ ofse,
    const unsigned* __restrict__ cntg,
    const float*    __restrict__ spikesT,
    float* __restrict__ out) {
  __shared__ int2  srt[CAP_SRT];               // 19.0 KB
  __shared__ unsigned cw[GP_][9];              // 18.4 KB (pad 9: no write conflicts)
  __shared__ unsigned short lpos[TPB][GP_ + 2];// 32.1 KB (pad: stride 257 u32)
  __shared__ unsigned short prt[16][TPB];      // 1 KB
  __shared__ unsigned short ttot[TPB];
  __shared__ float otile[TPB][33];             // 4.2 KB
  __shared__ unsigned sse[GP_];                // 2 KB
  __shared__ int ofs[TPB + 1];

  const int k = blockIdx.x, tid = threadIdx.x;
  const int b = tid & 31, hw = tid >> 5;       // hw 0..15

  sse[tid] = ofse[(size_t)tid * NBKT + k];     // strided (proven OK in R7/R8)
  {
    const uint4* cp = reinterpret_cast<const uint4*>(cntg + (size_t)tid * 4096 + k * 8);
    uint4 c0 = cp[0], c1 = cp[1];
    cw[tid][0] = c0.x; cw[tid][1] = c0.y; cw[tid][2] = c0.z; cw[tid][3] = c0.w;
    cw[tid][4] = c1.x; cw[tid][5] = c1.y; cw[tid][6] = c1.z; cw[tid][7] = c1.w;
  }
  __syncthreads();

  // 2D prefix over g per target: thread (tl=b, chunk=hw), 32 g's each
  const int wd = b >> 2, sh = 8 * (b & 3);
  {
    int s = 0;
    for (int j = 0; j < 32; ++j) s += (cw[hw * 32 + j][wd] >> sh) & 0xFF;
    prt[hw][b] = (unsigned short)s;
  }
  __syncthreads();
  {
    int pbase = 0;
    for (int c = 0; c < hw; ++c) pbase += prt[c][b];
    int run = pbase;
    for (int j = 0; j < 32; ++j) {
      lpos[b][hw * 32 + j] = (unsigned short)run;
      run += (cw[hw * 32 + j][wd] >> sh) & 0xFF;
    }
    if (hw == 15) ttot[b] = (unsigned short)run;
  }
  __syncthreads();
  if (tid < 32) {
    int v = ttot[tid], ii = v;
#pragma unroll
    for (int off = 1; off < 32; off <<= 1) {
      int u = __shfl_up(ii, off);
      if (tid >= off) ii += u;
    }
    ofs[tid] = ii - v;
    if (tid == 31) ofs[32] = ii;
  }
  __syncthreads();

  // place: 8-lane subgroup per slice (R8 pattern), exact slots, no atomics
  const int sub = b >> 3, j0 = b & 7;
  for (int it = 0; it < 8; ++it) {
    const int g = it * 64 + hw * 4 + sub;
    const unsigned u = sse[g];
    const int st = (int)(u & 0xFFFF);
    const int n  = (int)(u >> 16) - st;
    const int2* slice = rec + (size_t)g * EPG + st;
    for (int j = j0; j < n; j += 8) {
      int2 r = slice[j];
      const int tl  = (r.x >> 14) & 31;
      const int rk  = (r.x >> 19) & 31;
      const int idx = ofs[tl] + (int)lpos[tl][g] + rk;
      if (idx < CAP_SRT) srt[idx] = r;
    }
  }
  __syncthreads();

  // gather: half-wave hw owns targets hw (acc0), hw+16 (acc1); lane = batch
  float acc0 = 0.f, acc1 = 0.f;
  {
    int e        = min(ofs[hw], CAP_SRT);
    const int e1 = min(ofs[hw + 1], CAP_SRT);
    for (; e + 4 <= e1; e += 4) {
      int2 q0 = srt[e], q1 = srt[e + 1], q2 = srt[e + 2], q3 = srt[e + 3];
      float f0 = spikesT[(size_t)(q0.x & 0x3FFF) * 32 + b];
      float f1 = spikesT[(size_t)(q1.x & 0x3FFF) * 32 + b];
      float f2 = spikesT[(size_t)(q2.x & 0x3FFF) * 32 + b];
      float f3 = spikesT[(size_t)(q3.x & 0x3FFF) * 32 + b];
      acc0 = fmaf(__int_as_float(q0.y), f0, acc0);
      acc0 = fmaf(__int_as_float(q1.y), f1, acc0);
      acc0 = fmaf(__int_as_float(q2.y), f2, acc0);
      acc0 = fmaf(__int_as_float(q3.y), f3, acc0);
    }
    for (; e < e1; ++e) {
      int2 q = srt[e];
      acc0 = fmaf(__int_as_float(q.y), spikesT[(size_t)(q.x & 0x3FFF) * 32 + b], acc0);
    }
  }
  {
    int e        = min(ofs[hw + 16], CAP_SRT);
    const int e1 = min(ofs[hw + 17], CAP_SRT);
    for (; e + 4 <= e1; e += 4) {
      int2 q0 = srt[e], q1 = srt[e + 1], q2 = srt[e + 2], q3 = srt[e + 3];
      float f0 = spikesT[(size_t)(q0.x & 0x3FFF) * 32 + b];
      float f1 = spikesT[(size_t)(q1.x & 0x3FFF) * 32 + b];
      float f2 = spikesT[(size_t)(q2.x & 0x3FFF) * 32 + b];
      float f3 = spikesT[(size_t)(q3.x & 0x3FFF) * 32 + b];
      acc1 = fmaf(__int_as_float(q0.y), f0, acc1);
      acc1 = fmaf(__int_as_float(q1.y), f1, acc1);
      acc1 = fmaf(__int_as_float(q2.y), f2, acc1);
      acc1 = fmaf(__int_as_float(q3.y), f3, acc1);
    }
    for (; e < e1; ++e) {
      int2 q = srt[e];
      acc1 = fmaf(__int_as_float(q.y), spikesT[(size_t)(q.x & 0x3FFF) * 32 + b], acc1);
    }
  }

  // transpose 32x32 tile and write out coalesced
  otile[hw][b]      = acc0;
  otile[hw + 16][b] = acc1;
  __syncthreads();
  const int bb = tid >> 4;
  const int cc = (tid & 15) * 2;
  float2 o2 = make_float2(otile[cc][bb], otile[cc + 1][bb]);
  *reinterpret_cast<float2*>(&out[(size_t)bb * T_ + k * 32 + cc]) = o2;
}

// ---------------------------------------------------------------------------
__global__ void zero_floats(float* __restrict__ p, int n) {
  int i = blockIdx.x * blockDim.x + threadIdx.x;
  if (i < n) p[i] = 0.0f;
}

// Emergency fallback (tiny ws): direct global atomics, weights inline.
__global__ void naive_kernel(const float* __restrict__ spikes,
                             const float* __restrict__ att,
                             const int*   __restrict__ tgt,
                             const int*   __restrict__ del,
                             float*       __restrict__ out) {
  int i = blockIdx.x * blockDim.x + threadIdx.x;
  if (i >= NEDGES) return;
  int   s = i >> 6;
  int   t = tgt[i];
  float w = edge_weight(att[i], del[i]);
  for (int b = 0; b < B_; ++b)
    unsafeAtomicAdd(&out[(size_t)b * T_ + t], w * spikes[(size_t)b * S_ + s]);
}

// ---------------------------------------------------------------------------
extern "C" void kernel_launch(void* const* d_in, const int* in_sizes, int n_in,
                              void* d_out, int out_size, void* d_ws, size_t ws_size,
                              hipStream_t stream) {
  const float* spikes = (const float*)d_in[0];
  const float* att    = (const float*)d_in[1];
  const int*   tgt    = (const int*)d_in[2];
  const int*   del    = (const int*)d_in[3];
  float*       out    = (float*)d_out;

  const size_t spikesT_bytes = (size_t)S_ * B_ * sizeof(float);           // 2 MB
  const size_t rec_bytes     = (size_t)NEDGES * sizeof(int2);             // 8 MB
  const size_t cnt_bytes     = (size_t)GP_ * 4096 * sizeof(unsigned);     // 8 MB
  const size_t ofse_bytes    = (size_t)GP_ * NBKT * sizeof(unsigned);     // 1 MB
  const size_t need = spikesT_bytes + rec_bytes + cnt_bytes + ofse_bytes + 64;

  if (ws_size < need) {
    zero_floats<<<(B_ * T_ + 255) / 256, 256, 0, stream>>>(out, B_ * T_);
    naive_kernel<<<(NEDGES + 255) / 256, 256, 0, stream>>>(spikes, att, tgt, del, out);
    return;
  }

  char* p = (char*)d_ws;
  float*    spikesT = (float*)p;    p += spikesT_bytes;
  int2*     rec     = (int2*)p;     p += rec_bytes;
  unsigned* cntg    = (unsigned*)p; p += cnt_bytes;
  unsigned* ofse    = (unsigned*)p;

  produce<<<GP_, 512, 0, stream>>>(spikes, att, tgt, del, spikesT, rec, cntg, ofse);
  consume<<<NBKT, 512, 0, stream>>>(rec, ofse, cntg, spikesT, out);
}